// Round 9
// baseline (1129.097 us; speedup 1.0000x reference)
//
#include <hip/hip_runtime.h>

typedef unsigned short u16;
typedef unsigned int u32;
typedef __bf16 bf16x8 __attribute__((ext_vector_type(8)));
typedef float fx4 __attribute__((ext_vector_type(4)));
typedef float fx2 __attribute__((ext_vector_type(2)));

#define NT 262144      // B*T global tokens
#define B_SZ 512
#define T_LEN 512
#define NQv 1000
#define VE_ROWS 5120   // (q,r) table rows: 1001*5 = 5005, padded
#define TLP 264        // tile LDS row stride (u16): 256 + 8 pad
#define SSP 53         // summary LDS row stride (fp32)

__device__ __forceinline__ float bf2f(u16 u) { return __uint_as_float(((u32)u) << 16); }
__device__ __forceinline__ u16 f2bf(float f) {
    u32 x = __float_as_uint(f);
    x += 0x7fffu + ((x >> 16) & 1u);
    return (u16)(x >> 16);
}
__device__ __forceinline__ u32 pack2(float a, float b) {
    return (u32)f2bf(a) | ((u32)f2bf(b) << 16);
}
__device__ __forceinline__ float sigm(float x) { return 1.0f / (1.0f + __expf(-x)); }
__device__ __forceinline__ float tanh_fast(float x) {
    float e2 = __expf(2.0f * x);
    return 1.0f - 2.0f / (e2 + 1.0f);   // safe at +inf
}
__device__ __forceinline__ void load_lds16(const void* g, void* l) {
    __builtin_amdgcn_global_load_lds(
        (const __attribute__((address_space(1))) u32*)g,
        (__attribute__((address_space(3))) u32*)l, 16, 0, 0);
}

// ---------------- kernel 0 (MERGED prep): all precomputed tables in ONE launch ----------------
__global__ __launch_bounds__(256) void k_prep(const float* __restrict__ eW,
                                              const float* __restrict__ aW,
                                              const float* __restrict__ sW,
                                              const float* __restrict__ qeW,
                                              const float* __restrict__ Mk,
                                              const float* __restrict__ vW,
                                              const float* __restrict__ vb,
                                              const float* __restrict__ tW,
                                              const float* __restrict__ tb,
                                              const float* __restrict__ dW,
                                              const float* __restrict__ cW,
                                              u16* __restrict__ Wt,
                                              u16* __restrict__ SWt,
                                              float* __restrict__ w_tab,
                                              u16* __restrict__ ve_tab,
                                              float* __restrict__ sq_tab,
                                              float* __restrict__ beta_tab,
                                              float* __restrict__ dq_tab,
                                              float* __restrict__ cq_tab) {
    int bid = blockIdx.x;
    int tid = threadIdx.x;

    if (bid < 576) {
        int id = bid * 256 + tid;
        if (id < 131072) {
            int n = id >> 8, k = id & 255;
            Wt[n * 256 + k] = f2bf((n < 256) ? eW[k * 256 + n] : aW[k * 256 + (n - 256)]);
        } else {
            int id2 = id - 131072;
            if (id2 < 16384) {
                int n = id2 >> 8, k = id2 & 255;
                SWt[n * 256 + k] = (n < 50) ? f2bf(sW[k * 50 + n]) : (u16)0;
            }
        }
    } else if (bid < 580) {
        // ---- w_tab ----
        __shared__ __align__(16) float mk[3200];
        for (int i = tid; i < 3200; i += 256) mk[i] = Mk[i];
        int q = (bid - 576) * 256 + tid;
        __syncthreads();
        if (q > NQv) return;
        float qe[64];
        const float4* qr = (const float4*)(qeW + (size_t)q * 64);
#pragma unroll
        for (int i = 0; i < 16; i++) {
            float4 u = qr[i];
            qe[4 * i + 0] = u.x; qe[4 * i + 1] = u.y;
            qe[4 * i + 2] = u.z; qe[4 * i + 3] = u.w;
        }
        float lg[50];
#pragma unroll
        for (int m = 0; m < 50; m++) {
            const float* mr = &mk[m * 64];
            float acc = 0.f;
#pragma unroll
            for (int k = 0; k < 64; k++) acc = fmaf(qe[k], mr[k], acc);
            lg[m] = acc;
        }
        float mx = -1e30f;
#pragma unroll
        for (int m = 0; m < 50; m++) mx = fmaxf(mx, lg[m]);
        float sum = 0.f;
#pragma unroll
        for (int m = 0; m < 50; m++) { lg[m] = __expf(lg[m] - mx); sum += lg[m]; }
        float inv = 1.0f / sum;
#pragma unroll
        for (int m = 0; m < 50; m++) w_tab[(size_t)q * 50 + m] = lg[m] * inv;
    } else if (bid < 1220) {
        // ---- ve_tab ----
        int id = (bid - 580) * 256 + tid;
        int row = id >> 5, seg = id & 31;
        if (row >= VE_ROWS) return;
        int q = row / 5;
        int r = row - q * 5;
        if (q > NQv) q = NQv;
        int idx = (q > 0) ? (q - 1) : 0;
        float rs = (float)r * 0.25f;
        float vf = (q > 0) ? 1.0f : 0.0f;
        const float* pa = vW + (size_t)idx * 256 + seg * 8;
        const float* pb = pa + NQv * 256;
        float4 a0 = ((const float4*)pa)[0];
        float4 a1 = ((const float4*)pa)[1];
        float4 b0 = ((const float4*)pb)[0];
        float4 b1 = ((const float4*)pb)[1];
        const float* vbp = vb + seg * 8;
        float o0 = vf * fmaf(rs, b0.x, a0.x) + vbp[0];
        float o1 = vf * fmaf(rs, b0.y, a0.y) + vbp[1];
        float o2 = vf * fmaf(rs, b0.z, a0.z) + vbp[2];
        float o3 = vf * fmaf(rs, b0.w, a0.w) + vbp[3];
        float o4 = vf * fmaf(rs, b1.x, a1.x) + vbp[4];
        float o5 = vf * fmaf(rs, b1.y, a1.y) + vbp[5];
        float o6 = vf * fmaf(rs, b1.z, a1.z) + vbp[6];
        float o7 = vf * fmaf(rs, b1.w, a1.w) + vbp[7];
        uint4 o;
        o.x = pack2(o0, o1); o.y = pack2(o2, o3);
        o.z = pack2(o4, o5); o.w = pack2(o6, o7);
        *(uint4*)(ve_tab + (size_t)row * 256 + seg * 8) = o;
    } else {
        // ---- per-q head tables ----
        int id = (bid - 1220) * 256 + tid;
        int q = id >> 6, n = id & 63;
        if (q > NQv) return;
        float qe[64];
        const float4* qr = (const float4*)(qeW + (size_t)q * 64);
#pragma unroll
        for (int i = 0; i < 16; i++) {
            float4 u = qr[i];
            qe[4 * i + 0] = u.x; qe[4 * i + 1] = u.y;
            qe[4 * i + 2] = u.z; qe[4 * i + 3] = u.w;
        }
        if (n < 50) {
            float acc = 0.f;
#pragma unroll
            for (int k = 0; k < 64; k++) acc = fmaf(qe[k], sW[(256 + k) * 50 + n], acc);
            sq_tab[(size_t)q * 50 + n] = acc;
        } else if (n < 54) {
            int j = n - 50;
            float acc = tb[j];
#pragma unroll
            for (int k = 0; k < 64; k++) acc = fmaf(qe[k], tW[k * 4 + j], acc);
            beta_tab[(size_t)q * 4 + j] = acc;
        } else if (n == 54) {
            float acc = 0.f;
#pragma unroll
            for (int k = 0; k < 64; k++) acc = fmaf(qe[k], dW[50 + k], acc);
            dq_tab[q] = acc;
        } else if (n >= 56 && n < 60) {
            int j = n - 56;
            float acc = 0.f;
#pragma unroll
            for (int k = 0; k < 64; k++) acc = fmaf(qe[k], cW[(50 + k) * 4 + j], acc);
            cq_tab[(size_t)q * 4 + j] = acc;
        }
    }
}

// ---------------- kernel 2: erase/add MFMA GEMM over the (q,r) table (5120 rows) ----------------
__global__ __launch_bounds__(256) void k_gemm_ea(const u16* __restrict__ ve,
                                                 const u16* __restrict__ Wt,
                                                 const float* __restrict__ eb,
                                                 const float* __restrict__ ab,
                                                 u16* __restrict__ e_out,
                                                 u16* __restrict__ a_out) {
    __shared__ __align__(16) u16 smem[8192];   // lA[4096] | lB[4096]; reused as C-stage
    u16* lA = smem;
    u16* lB = smem + 4096;

    int tid = threadIdx.x;
    int row0 = blockIdx.x * 128;   // table-row space
    int col0 = blockIdx.y * 128;

    int wave = tid >> 6, lane = tid & 63;
    int wm = wave >> 1, wn = wave & 1;
    int rl = lane & 15, quad = lane >> 4;
    fx4 acc[4][4] = {};

    int c0 = tid, c1 = tid + 256;
    int r0_ = c0 >> 2, j0 = c0 & 3;
    int r1_ = c1 >> 2, j1 = c1 & 3;

    for (int k0 = 0; k0 < 256; k0 += 32) {
        load_lds16(ve + (size_t)(row0 + r0_) * 256 + k0 + j0 * 8, lA + c0 * 8);
        load_lds16(ve + (size_t)(row0 + r1_) * 256 + k0 + j1 * 8, lA + c1 * 8);
        load_lds16(Wt + (size_t)(col0 + r0_) * 256 + k0 + j0 * 8, lB + c0 * 8);
        load_lds16(Wt + (size_t)(col0 + r1_) * 256 + k0 + j1 * 8, lB + c1 * 8);
        __syncthreads();
        bf16x8 af[4], bfr[4];
#pragma unroll
        for (int i = 0; i < 4; i++) af[i] = *(const bf16x8*)(lA + (wm * 64 + i * 16 + rl) * 32 + quad * 8);
#pragma unroll
        for (int j = 0; j < 4; j++) bfr[j] = *(const bf16x8*)(lB + (wn * 64 + j * 16 + rl) * 32 + quad * 8);
#pragma unroll
        for (int i = 0; i < 4; i++)
#pragma unroll
            for (int j = 0; j < 4; j++)
                acc[i][j] = __builtin_amdgcn_mfma_f32_16x16x32_bf16(af[i], bfr[j], acc[i][j], 0, 0, 0);
        __syncthreads();
    }

    bool is_er = (col0 < 256);
    const float* bias = is_er ? eb : ab;
    u16* outp = is_er ? e_out : a_out;
    int cb0 = col0 & 255;
    u16* cst = smem;   // 8192 u16
#pragma unroll
    for (int h = 0; h < 2; h++) {
        if (wm == h) {
#pragma unroll
            for (int j = 0; j < 4; j++) {
                int nl = wn * 64 + j * 16 + rl;
                float bv = bias[cb0 + nl];
#pragma unroll
                for (int i = 0; i < 4; i++) {
                    int rowl = i * 16 + quad * 4;
#pragma unroll
                    for (int r = 0; r < 4; r++) {
                        float x = acc[i][j][r] + bv;
                        cst[(rowl + r) * 128 + nl] = f2bf(is_er ? sigm(x) : tanh_fast(x));
                    }
                }
            }
        }
        __syncthreads();
#pragma unroll
        for (int c = 0; c < 4; c++) {
            int idx = c * 256 + tid;
            int row = idx >> 4, seg = idx & 15;
            *(uint4*)(outp + (size_t)(row0 + h * 64 + row) * 256 + cb0 + seg * 8) =
                *(const uint4*)(cst + row * 128 + seg * 8);
        }
        __syncthreads();
    }
}

// ---------------- kernel 3: FUSED, producer-consumer wave split --------------------------------
// 512 threads: waves 0-3 (tid<256) run the proven R7 scan over 64-token tiles (double-buffered
// LDS); waves 4-7 consume the PREVIOUS tile (summary MFMA with SWt in consumer-only registers,
// sS overlay onto the consumed buffer, heads) spread across the existing per-group barriers.
// Consumer work (~32 MFMA + ~400 VALU ops/tile) hides entirely under the scan's ~25K cycles/tile.
// __launch_bounds__(512,4) caps VGPR at 128 so 2 blocks/CU stay resident (LDS 71.5KB x2 < 160KB).
__global__ __launch_bounds__(512, 4) void k_fused(const int* __restrict__ q_data,
                                                  const int* __restrict__ r_data,
                                                  const float* __restrict__ w_tab,
                                                  const u16* __restrict__ e_tab,
                                                  const u16* __restrict__ a_tab,
                                                  const float* __restrict__ Mv0,
                                                  const u16* __restrict__ SWt,
                                                  const float* __restrict__ sq_tab,
                                                  const float* __restrict__ sb,
                                                  const float* __restrict__ abilW,
                                                  const float* __restrict__ abilb,
                                                  const float* __restrict__ beta_tab,
                                                  const float* __restrict__ dW,
                                                  const float* __restrict__ db,
                                                  const float* __restrict__ dq_tab,
                                                  const float* __restrict__ cW,
                                                  const float* __restrict__ cb,
                                                  const float* __restrict__ cq_tab,
                                                  float* __restrict__ out) {
    int b = blockIdx.x;
    int tid = threadIdx.x;
    __shared__ __align__(16) u16 tileA[2][64 * TLP];   // 67,584 B double-buffered rd tiles
    __shared__ __align__(16) float wls[2][8][52];      // 3,328 B
    __shared__ int sq_idxS[64];                        // 256 B

    const int* qp = q_data + (size_t)b * T_LEN;
    const int* rp = r_data + (size_t)b * T_LEN;

    bool is_prod = (tid < 256);
    int ctid = tid - 256;              // consumer-local id [0,256)
    int clane = ctid & 63;
    int crl = clane & 15, cquad = clane >> 4;
    int cwave = ctid >> 6;             // 0..3
    int cwm = cwave >> 1, cwn = cwave & 1;

    fx2 Mv[25];                        // producer-only
    u16 eu[8], au[8];                  // producer-only
    bf16x8 swr[2][8];                  // consumer-only (64 VGPR on consumer waves)
    fx4 acc[2][2];                     // consumer-only

    if (is_prod) {
#pragma unroll
        for (int i = 0; i < 25; i++) {
            Mv[i].x = Mv0[(2 * i) * 256 + tid];
            Mv[i].y = Mv0[(2 * i + 1) * 256 + tid];
        }
#pragma unroll
        for (int s = 0; s < 8; s++) {
            int qr = qp[s] * 5 + rp[s];                       // uniform -> s_load
            eu[s] = e_tab[(size_t)qr * 256 + tid];
            au[s] = a_tab[(size_t)qr * 256 + tid];
        }
        if (tid < 200) {
            int s = tid / 25, m2 = tid % 25;
            float2 w0 = ((const float2*)(w_tab + (size_t)qp[s] * 50))[m2];
            wls[0][s][2 * m2] = w0.x;
            wls[0][s][2 * m2 + 1] = w0.y;
        }
    } else {
#pragma unroll
        for (int j = 0; j < 2; j++)
#pragma unroll
            for (int ks = 0; ks < 8; ks++)
                swr[j][ks] = *(const bf16x8*)(SWt + (size_t)(cwn * 32 + j * 16 + crl) * 256 + ks * 32 + cquad * 8);
    }
    __syncthreads();

    for (int t = 0; t < 9; t++) {                             // 8 producer tiles + 1 epilogue
        for (int gl = 0; gl < 8; gl++) {
            if (is_prod) {
                if (t < 8) {
                    int g = t * 8 + gl;                       // global group 0..63
                    int cur = g & 1, nxt = cur ^ 1;
                    bool has_next = (g + 1 < 64);
                    int tn0 = (g + 1) * 8;

                    u16 eun[8], aun[8];
                    float2 wn_ = make_float2(0.f, 0.f);
                    if (has_next) {
#pragma unroll
                        for (int s = 0; s < 8; s++) {
                            int qr = qp[tn0 + s] * 5 + rp[tn0 + s];   // uniform -> s_load
                            eun[s] = e_tab[(size_t)qr * 256 + tid];
                            aun[s] = a_tab[(size_t)qr * 256 + tid];
                        }
                        if (tid < 200) {
                            int s = tid / 25, m2 = tid % 25;
                            wn_ = ((const float2*)(w_tab + (size_t)qp[tn0 + s] * 50))[m2];
                        }
                    }

                    u16* tw = &tileA[t & 1][0];
#pragma unroll
                    for (int s = 0; s < 8; s++) {
                        float e = bf2f(eu[s]), a = bf2f(au[s]);
                        fx2 e2; e2.x = e; e2.y = e;
                        fx2 a2; a2.x = a; a2.y = a;
                        const fx2* wv = (const fx2*)&wls[cur][s][0];
                        fx2 rd2; rd2.x = 0.f; rd2.y = 0.f;
#pragma unroll
                        for (int i = 0; i < 25; i++) {
                            fx2 w2 = wv[i];                    // ds_read_b64 broadcast
                            rd2 = rd2 + w2 * Mv[i];            // read BEFORE write
                            fx2 t2 = a2 - e2 * Mv[i];          // a - e*Mv
                            Mv[i] = Mv[i] + w2 * t2;           // Mv + w*(a - e*Mv)
                        }
                        tw[(gl * 8 + s) * TLP + tid] = f2bf(rd2.x + rd2.y);
                    }

                    if (has_next) {
                        if (tid < 200) {
                            int s = tid / 25, m2 = tid % 25;
                            wls[nxt][s][2 * m2] = wn_.x;
                            wls[nxt][s][2 * m2 + 1] = wn_.y;
                        }
#pragma unroll
                        for (int s = 0; s < 8; s++) { eu[s] = eun[s]; au[s] = aun[s]; }
                    }
                }
            } else {
                if (t > 0) {
                    int tt = t - 1;
                    int buf = tt & 1;
                    int tile0 = tt * 64;
                    const u16* tA = &tileA[buf][0];
                    float* sS = (float*)&tileA[buf][0];        // overlay after MFMA reads done

                    if (gl == 0) {
                        if (ctid < 64) sq_idxS[ctid] = qp[tile0 + ctid];
                        fx4 z; z.x = 0.f; z.y = 0.f; z.z = 0.f; z.w = 0.f;
#pragma unroll
                        for (int i = 0; i < 2; i++)
#pragma unroll
                            for (int j = 0; j < 2; j++) acc[i][j] = z;
                    }
                    if (gl < 4) {
                        // 2 MFMA k-steps per chunk; tileA[buf] complete since last slot's barrier
#pragma unroll
                        for (int kk = 0; kk < 2; kk++) {
                            int ks = gl * 2 + kk;
                            int k0 = ks * 32;
                            bf16x8 af[2];
#pragma unroll
                            for (int i = 0; i < 2; i++)
                                af[i] = *(const bf16x8*)(tA + (cwm * 32 + i * 16 + crl) * TLP + k0 + cquad * 8);
#pragma unroll
                            for (int i = 0; i < 2; i++)
#pragma unroll
                                for (int j = 0; j < 2; j++)
                                    acc[i][j] = __builtin_amdgcn_mfma_f32_16x16x32_bf16(af[i], swr[j][ks], acc[i][j], 0, 0, 0);
                        }
                    } else if (gl == 4) {
                        // all consumer MFMA reads finished at the gl==3 barrier -> safe to overlay
#pragma unroll
                        for (int j = 0; j < 2; j++) {
                            int n = cwn * 32 + j * 16 + crl;
                            if (n < 50) {
#pragma unroll
                                for (int i = 0; i < 2; i++) {
                                    int rowl = cwm * 32 + i * 16 + cquad * 4;
#pragma unroll
                                    for (int r = 0; r < 4; r++)
                                        sS[(rowl + r) * SSP + n] = acc[i][j][r];
                                }
                            }
                        }
                    } else if (gl == 5) {
                        if (ctid < 64) {
                            int q = sq_idxS[ctid];
                            size_t gtok = (size_t)b * T_LEN + tile0 + ctid;
                            const float* sq = sq_tab + (size_t)q * 50;
                            const float* sp = sS + ctid * SSP;

                            float th = abilb[0];
                            float da = db[0];
                            float l0 = cb[0], l1 = cb[1], l2 = cb[2], l3 = cb[3];
#pragma unroll
                            for (int i = 0; i < 50; i++) {
                                float sv = tanh_fast(sp[i] + sq[i] + sb[i]);
                                th = fmaf(sv, abilW[i], th);
                                da = fmaf(sv, dW[i], da);
                                l0 = fmaf(sv, cW[i * 4 + 0], l0);
                                l1 = fmaf(sv, cW[i * 4 + 1], l1);
                                l2 = fmaf(sv, cW[i * 4 + 2], l2);
                                l3 = fmaf(sv, cW[i * 4 + 3], l3);
                            }
                            da += dq_tab[q];
                            l0 += cq_tab[q * 4 + 0];
                            l1 += cq_tab[q * 4 + 1];
                            l2 += cq_tab[q * 4 + 2];
                            l3 += cq_tab[q * 4 + 3];

                            out[gtok] = th * 3.0f;

                            out[NT + gtok * 4 + 0] = beta_tab[q * 4 + 0];
                            out[NT + gtok * 4 + 1] = beta_tab[q * 4 + 1];
                            out[NT + gtok * 4 + 2] = beta_tab[q * 4 + 2];
                            out[NT + gtok * 4 + 3] = beta_tab[q * 4 + 3];

                            out[5 * (size_t)NT + gtok] = logf(1.0f + __expf(da));

                            out[11 * (size_t)NT + gtok * 4 + 0] = l0;
                            out[11 * (size_t)NT + gtok * 4 + 1] = l1;
                            out[11 * (size_t)NT + gtok * 4 + 2] = l2;
                            out[11 * (size_t)NT + gtok * 4 + 3] = l3;

                            float c0 = sigm(l0);
                            float c1 = c0 * sigm(l1);
                            float c2 = c1 * sigm(l2);
                            float c3 = c2 * sigm(l3);
                            size_t pb = 6 * (size_t)NT + gtok * 5;
                            out[pb + 0] = 1.0f - c0;
                            out[pb + 1] = c0 - c1;
                            out[pb + 2] = c1 - c2;
                            out[pb + 3] = c2 - c3;
                            out[pb + 4] = c3;
                        }
                    }
                    // gl 6,7: consumer idle
                }
            }
            __syncthreads();
        }
    }
}

extern "C" void kernel_launch(void* const* d_in, const int* in_sizes, int n_in,
                              void* d_out, int out_size, void* d_ws, size_t ws_size,
                              hipStream_t stream) {
    (void)in_sizes; (void)n_in; (void)out_size; (void)ws_size;
    const int* q_data = (const int*)d_in[0];
    const int* r_data = (const int*)d_in[1];
    const float* qeW = (const float*)d_in[2];
    const float* Mk  = (const float*)d_in[3];
    const float* Mv0 = (const float*)d_in[4];
    const float* vW  = (const float*)d_in[5];
    const float* vb  = (const float*)d_in[6];
    const float* eW  = (const float*)d_in[7];
    const float* eb  = (const float*)d_in[8];
    const float* aW  = (const float*)d_in[9];
    const float* ab  = (const float*)d_in[10];
    const float* sW  = (const float*)d_in[11];
    const float* sb  = (const float*)d_in[12];
    const float* abilW = (const float*)d_in[13];
    const float* abilb = (const float*)d_in[14];
    const float* tW  = (const float*)d_in[15];
    const float* tb  = (const float*)d_in[16];
    const float* dW  = (const float*)d_in[17];
    const float* db  = (const float*)d_in[18];
    const float* cW  = (const float*)d_in[19];
    const float* cb  = (const float*)d_in[20];

    // workspace: ~8.6 MB total
    char* ws = (char*)d_ws;
    u16* Wt        = (u16*)(ws + 0);          // 262,144 B  bf16 [512][256]
    u16* SWt       = (u16*)(ws + 262144);     // 65,536 B   bf16 [64][256]
    float* w_tab   = (float*)(ws + 327680);   // 204,800 B  fp32 [1024][50]
    float* sq_tab  = (float*)(ws + 532480);   // 204,800 B  fp32 [1024][50]
    float* beta_tab= (float*)(ws + 737280);   // 16,384 B   fp32 [1024][4]
    float* dq_tab  = (float*)(ws + 753664);   // 4,096 B    fp32 [1024]
    float* cq_tab  = (float*)(ws + 757760);   // 16,384 B   fp32 [1024][4]
    u16* ve_tab    = (u16*)(ws + 774144);     // 2,621,440 B bf16 [5120][256]
    u16* e_tab     = (u16*)(ws + 3395584);    // 2,621,440 B
    u16* a_tab     = (u16*)(ws + 6017024);    // 2,621,440 B
    float* out = (float*)d_out;

    k_prep<<<1476, 256, 0, stream>>>(eW, aW, sW, qeW, Mk, vW, vb, tW, tb, dW, cW,
                                     Wt, SWt, w_tab, ve_tab,
                                     sq_tab, beta_tab, dq_tab, cq_tab);
    dim3 g2(VE_ROWS / 128, 4);
    k_gemm_ea<<<g2, 256, 0, stream>>>(ve_tab, Wt, eb, ab, e_tab, a_tab);
    k_fused<<<B_SZ, 512, 0, stream>>>(q_data, r_data, w_tab, e_tab, a_tab, Mv0,
                                      SWt, sq_tab, sb, abilW, abilb, beta_tab,
                                      dW, db, dq_tab, cW, cb, cq_tab, out);
}

// Round 10
// 429.359 us; speedup vs baseline: 2.6297x; 2.6297x over previous
//
#include <hip/hip_runtime.h>

typedef unsigned short u16;
typedef unsigned int u32;
typedef __bf16 bf16x8 __attribute__((ext_vector_type(8)));
typedef float fx4 __attribute__((ext_vector_type(4)));
typedef float fx2 __attribute__((ext_vector_type(2)));

#define NT 262144      // B*T global tokens
#define B_SZ 512
#define T_LEN 512
#define NQv 1000
#define VE_ROWS 5120   // (q,r) table rows: 1001*5 = 5005, padded
#define LP 40          // padded LDS stride for k_sum_heads staging
#define SSP 52         // summary LDS row stride (fp32)

__device__ __forceinline__ float bf2f(u16 u) { return __uint_as_float(((u32)u) << 16); }
__device__ __forceinline__ u16 f2bf(float f) {
    u32 x = __float_as_uint(f);
    x += 0x7fffu + ((x >> 16) & 1u);
    return (u16)(x >> 16);
}
__device__ __forceinline__ u32 pack2(float a, float b) {
    return (u32)f2bf(a) | ((u32)f2bf(b) << 16);
}
__device__ __forceinline__ float sigm(float x) { return 1.0f / (1.0f + __expf(-x)); }
__device__ __forceinline__ float tanh_fast(float x) {
    float e2 = __expf(2.0f * x);
    return 1.0f - 2.0f / (e2 + 1.0f);   // safe at +inf
}
__device__ __forceinline__ void load_lds16(const void* g, void* l) {
    __builtin_amdgcn_global_load_lds(
        (const __attribute__((address_space(1))) u32*)g,
        (__attribute__((address_space(3))) u32*)l, 16, 0, 0);
}

// ---------------- kernel 0 (MERGED prep): all precomputed tables in ONE launch ----------------
// blocks [0,576):   Wt/SWt transpose (bf16 B layouts)
// blocks [576,580): w_tab[q][50] softmax table
// blocks [580,1220): ve_tab[q*5+r][256] bf16
// blocks [1220,1476): sq/beta/dq/cq per-q head tables
__global__ __launch_bounds__(256) void k_prep(const float* __restrict__ eW,
                                              const float* __restrict__ aW,
                                              const float* __restrict__ sW,
                                              const float* __restrict__ qeW,
                                              const float* __restrict__ Mk,
                                              const float* __restrict__ vW,
                                              const float* __restrict__ vb,
                                              const float* __restrict__ tW,
                                              const float* __restrict__ tb,
                                              const float* __restrict__ dW,
                                              const float* __restrict__ cW,
                                              u16* __restrict__ Wt,
                                              u16* __restrict__ SWt,
                                              float* __restrict__ w_tab,
                                              u16* __restrict__ ve_tab,
                                              float* __restrict__ sq_tab,
                                              float* __restrict__ beta_tab,
                                              float* __restrict__ dq_tab,
                                              float* __restrict__ cq_tab) {
    int bid = blockIdx.x;
    int tid = threadIdx.x;

    if (bid < 576) {
        int id = bid * 256 + tid;
        if (id < 131072) {
            int n = id >> 8, k = id & 255;
            Wt[n * 256 + k] = f2bf((n < 256) ? eW[k * 256 + n] : aW[k * 256 + (n - 256)]);
        } else {
            int id2 = id - 131072;
            if (id2 < 16384) {
                int n = id2 >> 8, k = id2 & 255;
                SWt[n * 256 + k] = (n < 50) ? f2bf(sW[k * 50 + n]) : (u16)0;
            }
        }
    } else if (bid < 580) {
        // ---- w_tab ----
        __shared__ __align__(16) float mk[3200];
        for (int i = tid; i < 3200; i += 256) mk[i] = Mk[i];
        int q = (bid - 576) * 256 + tid;
        __syncthreads();
        if (q > NQv) return;
        float qe[64];
        const float4* qr = (const float4*)(qeW + (size_t)q * 64);
#pragma unroll
        for (int i = 0; i < 16; i++) {
            float4 u = qr[i];
            qe[4 * i + 0] = u.x; qe[4 * i + 1] = u.y;
            qe[4 * i + 2] = u.z; qe[4 * i + 3] = u.w;
        }
        float lg[50];
#pragma unroll
        for (int m = 0; m < 50; m++) {
            const float* mr = &mk[m * 64];
            float acc = 0.f;
#pragma unroll
            for (int k = 0; k < 64; k++) acc = fmaf(qe[k], mr[k], acc);
            lg[m] = acc;
        }
        float mx = -1e30f;
#pragma unroll
        for (int m = 0; m < 50; m++) mx = fmaxf(mx, lg[m]);
        float sum = 0.f;
#pragma unroll
        for (int m = 0; m < 50; m++) { lg[m] = __expf(lg[m] - mx); sum += lg[m]; }
        float inv = 1.0f / sum;
#pragma unroll
        for (int m = 0; m < 50; m++) w_tab[(size_t)q * 50 + m] = lg[m] * inv;
    } else if (bid < 1220) {
        // ---- ve_tab ----
        int id = (bid - 580) * 256 + tid;
        int row = id >> 5, seg = id & 31;
        if (row >= VE_ROWS) return;
        int q = row / 5;
        int r = row - q * 5;
        if (q > NQv) q = NQv;
        int idx = (q > 0) ? (q - 1) : 0;
        float rs = (float)r * 0.25f;
        float vf = (q > 0) ? 1.0f : 0.0f;
        const float* pa = vW + (size_t)idx * 256 + seg * 8;
        const float* pb = pa + NQv * 256;
        float4 a0 = ((const float4*)pa)[0];
        float4 a1 = ((const float4*)pa)[1];
        float4 b0 = ((const float4*)pb)[0];
        float4 b1 = ((const float4*)pb)[1];
        const float* vbp = vb + seg * 8;
        float o0 = vf * fmaf(rs, b0.x, a0.x) + vbp[0];
        float o1 = vf * fmaf(rs, b0.y, a0.y) + vbp[1];
        float o2 = vf * fmaf(rs, b0.z, a0.z) + vbp[2];
        float o3 = vf * fmaf(rs, b0.w, a0.w) + vbp[3];
        float o4 = vf * fmaf(rs, b1.x, a1.x) + vbp[4];
        float o5 = vf * fmaf(rs, b1.y, a1.y) + vbp[5];
        float o6 = vf * fmaf(rs, b1.z, a1.z) + vbp[6];
        float o7 = vf * fmaf(rs, b1.w, a1.w) + vbp[7];
        uint4 o;
        o.x = pack2(o0, o1); o.y = pack2(o2, o3);
        o.z = pack2(o4, o5); o.w = pack2(o6, o7);
        *(uint4*)(ve_tab + (size_t)row * 256 + seg * 8) = o;
    } else {
        // ---- per-q head tables ----
        int id = (bid - 1220) * 256 + tid;
        int q = id >> 6, n = id & 63;
        if (q > NQv) return;
        float qe[64];
        const float4* qr = (const float4*)(qeW + (size_t)q * 64);
#pragma unroll
        for (int i = 0; i < 16; i++) {
            float4 u = qr[i];
            qe[4 * i + 0] = u.x; qe[4 * i + 1] = u.y;
            qe[4 * i + 2] = u.z; qe[4 * i + 3] = u.w;
        }
        if (n < 50) {
            float acc = 0.f;
#pragma unroll
            for (int k = 0; k < 64; k++) acc = fmaf(qe[k], sW[(256 + k) * 50 + n], acc);
            sq_tab[(size_t)q * 50 + n] = acc;
        } else if (n < 54) {
            int j = n - 50;
            float acc = tb[j];
#pragma unroll
            for (int k = 0; k < 64; k++) acc = fmaf(qe[k], tW[k * 4 + j], acc);
            beta_tab[(size_t)q * 4 + j] = acc;
        } else if (n == 54) {
            float acc = 0.f;
#pragma unroll
            for (int k = 0; k < 64; k++) acc = fmaf(qe[k], dW[50 + k], acc);
            dq_tab[q] = acc;
        } else if (n >= 56 && n < 60) {
            int j = n - 56;
            float acc = 0.f;
#pragma unroll
            for (int k = 0; k < 64; k++) acc = fmaf(qe[k], cW[(50 + k) * 4 + j], acc);
            cq_tab[(size_t)q * 4 + j] = acc;
        }
    }
}

// ---------------- kernel 2: erase/add MFMA GEMM over the (q,r) table (5120 rows) ----------------
__global__ __launch_bounds__(256) void k_gemm_ea(const u16* __restrict__ ve,
                                                 const u16* __restrict__ Wt,
                                                 const float* __restrict__ eb,
                                                 const float* __restrict__ ab,
                                                 u16* __restrict__ e_out,
                                                 u16* __restrict__ a_out) {
    __shared__ __align__(16) u16 smem[8192];   // lA[4096] | lB[4096]; reused as C-stage
    u16* lA = smem;
    u16* lB = smem + 4096;

    int tid = threadIdx.x;
    int row0 = blockIdx.x * 128;   // table-row space
    int col0 = blockIdx.y * 128;

    int wave = tid >> 6, lane = tid & 63;
    int wm = wave >> 1, wn = wave & 1;
    int rl = lane & 15, quad = lane >> 4;
    fx4 acc[4][4] = {};

    int c0 = tid, c1 = tid + 256;
    int r0_ = c0 >> 2, j0 = c0 & 3;
    int r1_ = c1 >> 2, j1 = c1 & 3;

    for (int k0 = 0; k0 < 256; k0 += 32) {
        load_lds16(ve + (size_t)(row0 + r0_) * 256 + k0 + j0 * 8, lA + c0 * 8);
        load_lds16(ve + (size_t)(row0 + r1_) * 256 + k0 + j1 * 8, lA + c1 * 8);
        load_lds16(Wt + (size_t)(col0 + r0_) * 256 + k0 + j0 * 8, lB + c0 * 8);
        load_lds16(Wt + (size_t)(col0 + r1_) * 256 + k0 + j1 * 8, lB + c1 * 8);
        __syncthreads();
        bf16x8 af[4], bfr[4];
#pragma unroll
        for (int i = 0; i < 4; i++) af[i] = *(const bf16x8*)(lA + (wm * 64 + i * 16 + rl) * 32 + quad * 8);
#pragma unroll
        for (int j = 0; j < 4; j++) bfr[j] = *(const bf16x8*)(lB + (wn * 64 + j * 16 + rl) * 32 + quad * 8);
#pragma unroll
        for (int i = 0; i < 4; i++)
#pragma unroll
            for (int j = 0; j < 4; j++)
                acc[i][j] = __builtin_amdgcn_mfma_f32_16x16x32_bf16(af[i], bfr[j], acc[i][j], 0, 0, 0);
        __syncthreads();
    }

    bool is_er = (col0 < 256);
    const float* bias = is_er ? eb : ab;
    u16* outp = is_er ? e_out : a_out;
    int cb0 = col0 & 255;
    u16* cst = smem;   // 8192 u16
#pragma unroll
    for (int h = 0; h < 2; h++) {
        if (wm == h) {
#pragma unroll
            for (int j = 0; j < 4; j++) {
                int nl = wn * 64 + j * 16 + rl;
                float bv = bias[cb0 + nl];
#pragma unroll
                for (int i = 0; i < 4; i++) {
                    int rowl = i * 16 + quad * 4;
#pragma unroll
                    for (int r = 0; r < 4; r++) {
                        float x = acc[i][j][r] + bv;
                        cst[(rowl + r) * 128 + nl] = f2bf(is_er ? sigm(x) : tanh_fast(x));
                    }
                }
            }
        }
        __syncthreads();
#pragma unroll
        for (int c = 0; c < 4; c++) {
            int idx = c * 256 + tid;
            int row = idx >> 4, seg = idx & 15;
            *(uint4*)(outp + (size_t)(row0 + h * 64 + row) * 256 + cb0 + seg * 8) =
                *(const uint4*)(cst + row * 128 + seg * 8);
        }
        __syncthreads();
    }
}

// ---------------- kernel 3: scan over full T=512, table-gathered w/e/a (R6, measured 300us) ----
__global__ __launch_bounds__(256) void k_scan(const int* __restrict__ q_data,
                                              const int* __restrict__ r_data,
                                              const float* __restrict__ w_tab,
                                              const u16* __restrict__ e_tab,
                                              const u16* __restrict__ a_tab,
                                              const float* __restrict__ Mv0,
                                              u16* __restrict__ reads_out) {
    int b = blockIdx.x;
    int tid = threadIdx.x;
    __shared__ float wls[2][8][52];

    const int* qp = q_data + (size_t)b * T_LEN;
    const int* rp = r_data + (size_t)b * T_LEN;

    fx2 Mv[25];
#pragma unroll
    for (int i = 0; i < 25; i++) {
        Mv[i].x = Mv0[(2 * i) * 256 + tid];
        Mv[i].y = Mv0[(2 * i + 1) * 256 + tid];
    }

    u16 eu[8], au[8];
#pragma unroll
    for (int s = 0; s < 8; s++) {
        int qr = qp[s] * 5 + rp[s];                       // uniform -> s_load
        eu[s] = e_tab[(size_t)qr * 256 + tid];
        au[s] = a_tab[(size_t)qr * 256 + tid];
    }
    if (tid < 200) {
        int s = tid / 25, m2 = tid % 25;
        float2 w0 = ((const float2*)(w_tab + (size_t)qp[s] * 50))[m2];
        wls[0][s][2 * m2] = w0.x;
        wls[0][s][2 * m2 + 1] = w0.y;
    }
    __syncthreads();

    const int ngrp = T_LEN / 8;
    for (int g = 0; g < ngrp; g++) {
        int cur = g & 1, nxt = cur ^ 1;
        bool has_next = (g + 1 < ngrp);
        int tn0 = (g + 1) * 8;

        u16 eun[8], aun[8];
        float2 wn_ = make_float2(0.f, 0.f);
        if (has_next) {
#pragma unroll
            for (int s = 0; s < 8; s++) {
                int qr = qp[tn0 + s] * 5 + rp[tn0 + s];   // uniform -> s_load
                eun[s] = e_tab[(size_t)qr * 256 + tid];
                aun[s] = a_tab[(size_t)qr * 256 + tid];
            }
            if (tid < 200) {
                int s = tid / 25, m2 = tid % 25;
                wn_ = ((const float2*)(w_tab + (size_t)qp[tn0 + s] * 50))[m2];
            }
        }

#pragma unroll
        for (int s = 0; s < 8; s++) {
            float e = bf2f(eu[s]), a = bf2f(au[s]);
            fx2 e2; e2.x = e; e2.y = e;
            fx2 a2; a2.x = a; a2.y = a;
            const fx2* wv = (const fx2*)&wls[cur][s][0];
            fx2 rd2; rd2.x = 0.f; rd2.y = 0.f;
#pragma unroll
            for (int i = 0; i < 25; i++) {
                fx2 w2 = wv[i];                            // ds_read_b64 broadcast
                rd2 = rd2 + w2 * Mv[i];                    // read BEFORE write
                fx2 t2 = a2 - e2 * Mv[i];                  // a - e*Mv
                Mv[i] = Mv[i] + w2 * t2;                   // Mv + w*(a - e*Mv)
            }
            float rd = rd2.x + rd2.y;
            reads_out[((size_t)b * T_LEN + g * 8 + s) * 256 + tid] = f2bf(rd);
        }

        if (has_next) {
            if (tid < 200) {
                int s = tid / 25, m2 = tid % 25;
                wls[nxt][s][2 * m2] = wn_.x;
                wls[nxt][s][2 * m2 + 1] = wn_.y;
            }
#pragma unroll
            for (int s = 0; s < 8; s++) { eu[s] = eun[s]; au[s] = aun[s]; }
        }
        __syncthreads();
    }
}

// ---------------- kernel 4: summary MFMA + heads via per-q tables (K=256, 8 k-steps) ----------
__global__ __launch_bounds__(256) void k_sum_heads(const u16* __restrict__ reads,
                                                   const int* __restrict__ q_data,
                                                   const u16* __restrict__ SWt,
                                                   const float* __restrict__ sq_tab,
                                                   const float* __restrict__ sb,
                                                   const float* __restrict__ abilW,
                                                   const float* __restrict__ abilb,
                                                   const float* __restrict__ beta_tab,
                                                   const float* __restrict__ dW,
                                                   const float* __restrict__ db,
                                                   const float* __restrict__ dq_tab,
                                                   const float* __restrict__ cW,
                                                   const float* __restrict__ cb,
                                                   const float* __restrict__ cq_tab,
                                                   float* __restrict__ out) {
    __shared__ __align__(16) u16 lA[128 * LP];
    __shared__ __align__(16) u16 lB[64 * LP];
    __shared__ float sS[128 * SSP];
    __shared__ int s_q[128];
    int tid = threadIdx.x;
    int row0 = blockIdx.x * 128;           // token space (gtok = b*T + t, contiguous)
    if (tid < 128) s_q[tid] = q_data[row0 + tid];
    int wave = tid >> 6, lane = tid & 63;
    int wm = wave >> 1, wn = wave & 1;
    int rl = lane & 15, quad = lane >> 4;
    fx4 acc[4][2] = {};
    __syncthreads();

    for (int ks = 0; ks < 8; ks++) {
        int k0 = ks * 32;
#pragma unroll
        for (int h = 0; h < 2; h++) {
            int c = tid + h * 256;
            int row = c >> 2, j = c & 3;
            uint4 u = *(const uint4*)(reads + (size_t)(row0 + row) * 256 + k0 + j * 8);
            *(uint4*)(lA + row * LP + j * 8) = u;
        }
        {
            int n = tid >> 2, j = tid & 3;
            uint4 u = *(const uint4*)(SWt + (size_t)n * 256 + k0 + j * 8);
            *(uint4*)(lB + n * LP + j * 8) = u;
        }
        __syncthreads();
        bf16x8 af[4], bfr[2];
#pragma unroll
        for (int i = 0; i < 4; i++) af[i] = *(const bf16x8*)(lA + (wm * 64 + i * 16 + rl) * LP + quad * 8);
#pragma unroll
        for (int j = 0; j < 2; j++) bfr[j] = *(const bf16x8*)(lB + (wn * 32 + j * 16 + rl) * LP + quad * 8);
#pragma unroll
        for (int i = 0; i < 4; i++)
#pragma unroll
            for (int j = 0; j < 2; j++)
                acc[i][j] = __builtin_amdgcn_mfma_f32_16x16x32_bf16(af[i], bfr[j], acc[i][j], 0, 0, 0);
        __syncthreads();
    }

#pragma unroll
    for (int j = 0; j < 2; j++) {
        int n = wn * 32 + j * 16 + rl;
        if (n < 50) {
#pragma unroll
            for (int i = 0; i < 4; i++) {
                int rowl = wm * 64 + i * 16 + quad * 4;
#pragma unroll
                for (int r = 0; r < 4; r++)
                    sS[(rowl + r) * SSP + n] = acc[i][j][r];
            }
        }
    }
    __syncthreads();

    if (tid < 128) {
        int q = s_q[tid];
        size_t gtok = (size_t)row0 + tid;
        const float* sq = sq_tab + (size_t)q * 50;
        const float* sp = &sS[tid * SSP];

        float th = abilb[0];
        float da = db[0];
        float l0 = cb[0], l1 = cb[1], l2 = cb[2], l3 = cb[3];
#pragma unroll
        for (int i = 0; i < 50; i++) {
            float sv = tanh_fast(sp[i] + sq[i] + sb[i]);
            th = fmaf(sv, abilW[i], th);
            da = fmaf(sv, dW[i], da);
            l0 = fmaf(sv, cW[i * 4 + 0], l0);
            l1 = fmaf(sv, cW[i * 4 + 1], l1);
            l2 = fmaf(sv, cW[i * 4 + 2], l2);
            l3 = fmaf(sv, cW[i * 4 + 3], l3);
        }
        da += dq_tab[q];
        l0 += cq_tab[q * 4 + 0];
        l1 += cq_tab[q * 4 + 1];
        l2 += cq_tab[q * 4 + 2];
        l3 += cq_tab[q * 4 + 3];

        out[gtok] = th * 3.0f;

        out[NT + gtok * 4 + 0] = beta_tab[q * 4 + 0];
        out[NT + gtok * 4 + 1] = beta_tab[q * 4 + 1];
        out[NT + gtok * 4 + 2] = beta_tab[q * 4 + 2];
        out[NT + gtok * 4 + 3] = beta_tab[q * 4 + 3];

        out[5 * (size_t)NT + gtok] = logf(1.0f + __expf(da));

        out[11 * (size_t)NT + gtok * 4 + 0] = l0;
        out[11 * (size_t)NT + gtok * 4 + 1] = l1;
        out[11 * (size_t)NT + gtok * 4 + 2] = l2;
        out[11 * (size_t)NT + gtok * 4 + 3] = l3;

        float c0 = sigm(l0);
        float c1 = c0 * sigm(l1);
        float c2 = c1 * sigm(l2);
        float c3 = c2 * sigm(l3);
        size_t pb = 6 * (size_t)NT + gtok * 5;
        out[pb + 0] = 1.0f - c0;
        out[pb + 1] = c0 - c1;
        out[pb + 2] = c1 - c2;
        out[pb + 3] = c2 - c3;
        out[pb + 4] = c3;
    }
}

extern "C" void kernel_launch(void* const* d_in, const int* in_sizes, int n_in,
                              void* d_out, int out_size, void* d_ws, size_t ws_size,
                              hipStream_t stream) {
    (void)in_sizes; (void)n_in; (void)out_size; (void)ws_size;
    const int* q_data = (const int*)d_in[0];
    const int* r_data = (const int*)d_in[1];
    const float* qeW = (const float*)d_in[2];
    const float* Mk  = (const float*)d_in[3];
    const float* Mv0 = (const float*)d_in[4];
    const float* vW  = (const float*)d_in[5];
    const float* vb  = (const float*)d_in[6];
    const float* eW  = (const float*)d_in[7];
    const float* eb  = (const float*)d_in[8];
    const float* aW  = (const float*)d_in[9];
    const float* ab  = (const float*)d_in[10];
    const float* sW  = (const float*)d_in[11];
    const float* sb  = (const float*)d_in[12];
    const float* abilW = (const float*)d_in[13];
    const float* abilb = (const float*)d_in[14];
    const float* tW  = (const float*)d_in[15];
    const float* tb  = (const float*)d_in[16];
    const float* dW  = (const float*)d_in[17];
    const float* db  = (const float*)d_in[18];
    const float* cW  = (const float*)d_in[19];
    const float* cb  = (const float*)d_in[20];

    // workspace: ~143 MB total
    char* ws = (char*)d_ws;
    u16* Wt        = (u16*)(ws + 0);          // 262,144 B  bf16 [512][256]
    u16* SWt       = (u16*)(ws + 262144);     // 65,536 B   bf16 [64][256]
    float* w_tab   = (float*)(ws + 327680);   // 204,800 B  fp32 [1024][50]
    float* sq_tab  = (float*)(ws + 532480);   // 204,800 B  fp32 [1024][50]
    float* beta_tab= (float*)(ws + 737280);   // 16,384 B   fp32 [1024][4]
    float* dq_tab  = (float*)(ws + 753664);   // 4,096 B    fp32 [1024]
    float* cq_tab  = (float*)(ws + 757760);   // 16,384 B   fp32 [1024][4]
    u16* ve_tab    = (u16*)(ws + 774144);     // 2,621,440 B bf16 [5120][256]
    u16* e_tab     = (u16*)(ws + 3395584);    // 2,621,440 B
    u16* a_tab     = (u16*)(ws + 6017024);    // 2,621,440 B
    u16* reads     = (u16*)(ws + 8638464);    // 134,217,728 B bf16 [262144][256]
    float* out = (float*)d_out;

    k_prep<<<1476, 256, 0, stream>>>(eW, aW, sW, qeW, Mk, vW, vb, tW, tb, dW, cW,
                                     Wt, SWt, w_tab, ve_tab,
                                     sq_tab, beta_tab, dq_tab, cq_tab);
    dim3 g2(VE_ROWS / 128, 4);
    k_gemm_ea<<<g2, 256, 0, stream>>>(ve_tab, Wt, eb, ab, e_tab, a_tab);
    k_scan<<<B_SZ, 256, 0, stream>>>(q_data, r_data, w_tab, e_tab, a_tab, Mv0, reads);
    k_sum_heads<<<NT / 128, 256, 0, stream>>>(reads, q_data, SWt, sq_tab, sb,
                                              abilW, abilb, beta_tab, dW, db, dq_tab,
                                              cW, cb, cq_tab, out);
}